// Round 1
// baseline (2082.757 us; speedup 1.0000x reference)
//
#include <hip/hip_runtime.h>

#define NN 50000
#define NE 800000
#define INC 128
#define HIDC 64
#define NL 14
#define EPS_MSG 1e-7f
#define EPS_SM 1e-16f
#define LN_EPS 1e-5f

#define SCAN_B 256
#define NB_SCAN ((NN + SCAN_B - 1) / SCAN_B)   // 196

__device__ __forceinline__ float wave_sum(float v) {
    #pragma unroll
    for (int o = 32; o > 0; o >>= 1) v += __shfl_xor(v, o, 64);
    return v;
}
__device__ __forceinline__ float wave_max(float v) {
    #pragma unroll
    for (int o = 32; o > 0; o >>= 1) v = fmaxf(v, __shfl_xor(v, o, 64));
    return v;
}

// ---------------- CSR build ----------------
__global__ void k_hist(const int* __restrict__ dst, int* __restrict__ deg) {
    int i = blockIdx.x * blockDim.x + threadIdx.x;
    if (i < NE) atomicAdd(&deg[dst[i]], 1);
}

__global__ void k_part(const int* __restrict__ deg, int* __restrict__ part) {
    __shared__ int sm[SCAN_B];
    int b = blockIdx.x;
    int i = b * SCAN_B + threadIdx.x;
    sm[threadIdx.x] = (i < NN) ? deg[i] : 0;
    __syncthreads();
    for (int s = SCAN_B / 2; s > 0; s >>= 1) {
        if (threadIdx.x < s) sm[threadIdx.x] += sm[threadIdx.x + s];
        __syncthreads();
    }
    if (threadIdx.x == 0) part[b] = sm[0];
}

__global__ void k_scanpart(const int* __restrict__ part, int* __restrict__ partOfs) {
    __shared__ int sm[SCAN_B];
    int t = threadIdx.x;
    int own = (t < NB_SCAN) ? part[t] : 0;
    sm[t] = own;
    __syncthreads();
    for (int o = 1; o < SCAN_B; o <<= 1) {
        int v = (t >= o) ? sm[t - o] : 0;
        __syncthreads();
        sm[t] += v;
        __syncthreads();
    }
    if (t < NB_SCAN) partOfs[t] = sm[t] - own;   // exclusive
}

__global__ void k_scanfinal(const int* __restrict__ deg, const int* __restrict__ partOfs,
                            int* __restrict__ rowOfs) {
    __shared__ int sm[SCAN_B];
    int b = blockIdx.x, t = threadIdx.x;
    int i = b * SCAN_B + t;
    int d = (i < NN) ? deg[i] : 0;
    sm[t] = d;
    __syncthreads();
    for (int o = 1; o < SCAN_B; o <<= 1) {
        int v = (t >= o) ? sm[t - o] : 0;
        __syncthreads();
        sm[t] += v;
        __syncthreads();
    }
    if (i < NN) rowOfs[i] = partOfs[b] + sm[t] - d;
    if (i == 0) rowOfs[NN] = NE;
}

__global__ void k_scatter(const int* __restrict__ src, const int* __restrict__ dst,
                          const int* __restrict__ rowOfs, int* __restrict__ cur,
                          int* __restrict__ csr) {
    int i = blockIdx.x * blockDim.x + threadIdx.x;
    if (i < NE) {
        int d = dst[i];
        int p = rowOfs[d] + atomicAdd(&cur[d], 1);
        csr[p] = src[i];
    }
}

// ---------------- encoder: h = x @ encW + encb ----------------
__global__ __launch_bounds__(256) void k_enc(const float* __restrict__ x,
                                             const float* __restrict__ W,
                                             const float* __restrict__ b,
                                             float* __restrict__ h) {
    __shared__ float WL[INC * HIDC];
    for (int i = threadIdx.x; i < INC * HIDC; i += 256) WL[i] = W[i];
    __syncthreads();
    int lane = threadIdx.x & 63;
    int wid = (blockIdx.x * 256 + threadIdx.x) >> 6;
    int nw = (gridDim.x * 256) >> 6;
    for (int r = wid; r < NN; r += nw) {
        float x0 = x[r * INC + lane];
        float x1 = x[r * INC + 64 + lane];
        float acc = b[lane];
        #pragma unroll
        for (int k = 0; k < 64; k++) acc = fmaf(__shfl(x0, k, 64), WL[k * HIDC + lane], acc);
        #pragma unroll
        for (int k = 0; k < 64; k++) acc = fmaf(__shfl(x1, k, 64), WL[(64 + k) * HIDC + lane], acc);
        h[r * HIDC + lane] = acc;
    }
}

// ---------------- LN + ReLU ----------------
__global__ __launch_bounds__(256) void k_lnrelu(const float* __restrict__ h,
                                                float* __restrict__ y) {
    int lane = threadIdx.x & 63;
    int wid = (blockIdx.x * 256 + threadIdx.x) >> 6;
    if (wid >= NN) return;
    float v = h[wid * HIDC + lane];
    float mu = wave_sum(v) * (1.f / 64.f);
    float d = v - mu;
    float var = wave_sum(d * d) * (1.f / 64.f);
    float out = fmaxf(d * rsqrtf(var + LN_EPS), 0.f);
    y[wid * HIDC + lane] = out;
}

// ---------------- edge softmax-aggregation (one wave per dst node) ----------------
__global__ __launch_bounds__(256) void k_aggr(const float* __restrict__ y,
                                              const int* __restrict__ rowOfs,
                                              const int* __restrict__ csr,
                                              const float* __restrict__ tptr,
                                              float* __restrict__ aggr) {
    int lane = threadIdx.x & 63;
    int v = (blockIdx.x * 256 + threadIdx.x) >> 6;
    if (v >= NN) return;
    float t = *tptr;
    int e0 = rowOfs[v], e1 = rowOfs[v + 1];
    float se = 0.f, sw = 0.f;
    for (int e = e0; e < e1; e++) {
        int s = csr[e];
        float g = fmaxf(y[s * HIDC + lane], 0.f) + EPS_MSG;
        float w = __expf(t * g);
        se += w;
        sw = fmaf(g, w, sw);
    }
    aggr[v * HIDC + lane] = sw / (se + EPS_SM);
}

// ---------------- out = (aggr + y) @ W + b (+ residual) ----------------
__global__ __launch_bounds__(256) void k_gemm64(const float* __restrict__ aggr,
                                                const float* __restrict__ y,
                                                const float* __restrict__ W,
                                                const float* __restrict__ b,
                                                const float* __restrict__ hres,
                                                float* __restrict__ hout) {
    __shared__ float WL[HIDC * HIDC];
    for (int i = threadIdx.x; i < HIDC * HIDC; i += 256) WL[i] = W[i];
    __syncthreads();
    int lane = threadIdx.x & 63;
    int wid = (blockIdx.x * 256 + threadIdx.x) >> 6;
    int nw = (gridDim.x * 256) >> 6;
    for (int r = wid; r < NN; r += nw) {
        float a = aggr[r * HIDC + lane] + y[r * HIDC + lane];
        float acc = b[lane] + (hres ? hres[r * HIDC + lane] : 0.f);
        #pragma unroll
        for (int k = 0; k < 64; k++) acc = fmaf(__shfl(a, k, 64), WL[k * HIDC + lane], acc);
        hout[r * HIDC + lane] = acc;
    }
}

// ---------------- final LN + ReLU + log_softmax ----------------
__global__ __launch_bounds__(256) void k_final(const float* __restrict__ h,
                                               float* __restrict__ out) {
    int lane = threadIdx.x & 63;
    int wid = (blockIdx.x * 256 + threadIdx.x) >> 6;
    if (wid >= NN) return;
    float v = h[wid * HIDC + lane];
    float mu = wave_sum(v) * (1.f / 64.f);
    float d = v - mu;
    float var = wave_sum(d * d) * (1.f / 64.f);
    float z = fmaxf(d * rsqrtf(var + LN_EPS), 0.f);
    float m = wave_max(z);
    float s = wave_sum(__expf(z - m));
    out[wid * HIDC + lane] = z - (m + __logf(s));
}

extern "C" void kernel_launch(void* const* d_in, const int* in_sizes, int n_in,
                              void* d_out, int out_size, void* d_ws, size_t ws_size,
                              hipStream_t stream) {
    const float* x    = (const float*)d_in[0];
    const int*   ei   = (const int*)d_in[1];
    const float* encW = (const float*)d_in[2];
    const float* encb = (const float*)d_in[3];
    const float* mlpW = (const float*)d_in[4];
    const float* mlpb = (const float*)d_in[5];
    const float* t    = (const float*)d_in[6];

    float* h = (float*)d_out;   // [NN, 64] working buffer doubles as output

    char* ws = (char*)d_ws;
    size_t off = 0;
    auto alloc = [&](size_t bytes) -> void* {
        void* p = ws + off;
        off += (bytes + 255) / 256 * 256;
        return p;
    };
    float* y      = (float*)alloc((size_t)NN * HIDC * 4);
    float* aggr   = (float*)alloc((size_t)NN * HIDC * 4);
    int*   deg    = (int*)alloc((size_t)NN * 4);
    int*   cur    = (int*)alloc((size_t)NN * 4);
    int*   rowOfs = (int*)alloc((size_t)(NN + 1) * 4);
    int*   part   = (int*)alloc((size_t)NB_SCAN * 4);
    int*   partOf = (int*)alloc((size_t)NB_SCAN * 4);
    int*   csr    = (int*)alloc((size_t)NE * 4);

    const int* src = ei;
    const int* dst = ei + NE;

    hipMemsetAsync(deg, 0, (size_t)NN * 4, stream);
    hipMemsetAsync(cur, 0, (size_t)NN * 4, stream);

    k_hist<<<(NE + 255) / 256, 256, 0, stream>>>(dst, deg);
    k_part<<<NB_SCAN, SCAN_B, 0, stream>>>(deg, part);
    k_scanpart<<<1, SCAN_B, 0, stream>>>(part, partOf);
    k_scanfinal<<<NB_SCAN, SCAN_B, 0, stream>>>(deg, partOf, rowOfs);
    k_scatter<<<(NE + 255) / 256, 256, 0, stream>>>(src, dst, rowOfs, cur, csr);

    k_enc<<<2048, 256, 0, stream>>>(x, encW, encb, h);

    // layer 0: no pre-norm, input h, no residual
    k_aggr<<<12500, 256, 0, stream>>>(h, rowOfs, csr, t, aggr);
    k_gemm64<<<2048, 256, 0, stream>>>(aggr, h, mlpW, mlpb, nullptr, h);

    for (int l = 1; l < NL; l++) {
        k_lnrelu<<<12500, 256, 0, stream>>>(h, y);
        k_aggr<<<12500, 256, 0, stream>>>(y, rowOfs, csr, t + l, aggr);
        k_gemm64<<<2048, 256, 0, stream>>>(aggr, y, mlpW + (size_t)l * HIDC * HIDC,
                                           mlpb + (size_t)l * HIDC, h, h);
    }

    k_final<<<12500, 256, 0, stream>>>(h, h);
}

// Round 3
// 1347.237 us; speedup vs baseline: 1.5459x; 1.5459x over previous
//
#include <hip/hip_runtime.h>

#define NN 50000
#define NE 800000
#define INC 128
#define HIDC 64
#define NL 14
#define EPS_MSG 1e-7f
#define EPS_SM 1e-16f
#define LN_EPS 1e-5f

#define SCAN_B 256
#define NB_SCAN ((NN + SCAN_B - 1) / SCAN_B)   // 196

__device__ __forceinline__ float wave_sum(float v) {
    #pragma unroll
    for (int o = 32; o > 0; o >>= 1) v += __shfl_xor(v, o, 64);
    return v;
}
__device__ __forceinline__ float wave_max(float v) {
    #pragma unroll
    for (int o = 32; o > 0; o >>= 1) v = fmaxf(v, __shfl_xor(v, o, 64));
    return v;
}

// ---------------- CSR build ----------------
__global__ void k_hist(const int* __restrict__ dst, int* __restrict__ deg) {
    int i = blockIdx.x * blockDim.x + threadIdx.x;
    if (i < NE) atomicAdd(&deg[dst[i]], 1);
}

__global__ void k_part(const int* __restrict__ deg, int* __restrict__ part) {
    __shared__ int sm[SCAN_B];
    int b = blockIdx.x;
    int i = b * SCAN_B + threadIdx.x;
    sm[threadIdx.x] = (i < NN) ? deg[i] : 0;
    __syncthreads();
    for (int s = SCAN_B / 2; s > 0; s >>= 1) {
        if (threadIdx.x < s) sm[threadIdx.x] += sm[threadIdx.x + s];
        __syncthreads();
    }
    if (threadIdx.x == 0) part[b] = sm[0];
}

__global__ void k_scanpart(const int* __restrict__ part, int* __restrict__ partOfs) {
    __shared__ int sm[SCAN_B];
    int t = threadIdx.x;
    int own = (t < NB_SCAN) ? part[t] : 0;
    sm[t] = own;
    __syncthreads();
    for (int o = 1; o < SCAN_B; o <<= 1) {
        int v = (t >= o) ? sm[t - o] : 0;
        __syncthreads();
        sm[t] += v;
        __syncthreads();
    }
    if (t < NB_SCAN) partOfs[t] = sm[t] - own;   // exclusive
}

__global__ void k_scanfinal(const int* __restrict__ deg, const int* __restrict__ partOfs,
                            int* __restrict__ rowOfs) {
    __shared__ int sm[SCAN_B];
    int b = blockIdx.x, t = threadIdx.x;
    int i = b * SCAN_B + t;
    int d = (i < NN) ? deg[i] : 0;
    sm[t] = d;
    __syncthreads();
    for (int o = 1; o < SCAN_B; o <<= 1) {
        int v = (t >= o) ? sm[t - o] : 0;
        __syncthreads();
        sm[t] += v;
        __syncthreads();
    }
    if (i < NN) rowOfs[i] = partOfs[b] + sm[t] - d;
    if (i == 0) rowOfs[NN] = NE;
}

__global__ void k_scatter(const int* __restrict__ src, const int* __restrict__ dst,
                          const int* __restrict__ rowOfs, int* __restrict__ cur,
                          int* __restrict__ csr) {
    int i = blockIdx.x * blockDim.x + threadIdx.x;
    if (i < NE) {
        int d = dst[i];
        int p = rowOfs[d] + atomicAdd(&cur[d], 1);
        csr[p] = src[i];
    }
}

// ---------------- encoder: h = x @ encW + encb ----------------
__global__ __launch_bounds__(256) void k_enc(const float* __restrict__ x,
                                             const float* __restrict__ W,
                                             const float* __restrict__ b,
                                             float* __restrict__ h) {
    __shared__ float WL[INC * HIDC];
    for (int i = threadIdx.x; i < INC * HIDC; i += 256) WL[i] = W[i];
    __syncthreads();
    int lane = threadIdx.x & 63;
    int wid = (blockIdx.x * 256 + threadIdx.x) >> 6;
    int nw = (gridDim.x * 256) >> 6;
    for (int r = wid; r < NN; r += nw) {
        float x0 = x[r * INC + lane];
        float x1 = x[r * INC + 64 + lane];
        float a0 = 0.f, a1 = 0.f, a2 = 0.f, a3 = 0.f;
        #pragma unroll
        for (int k = 0; k < 64; k += 4) {
            a0 = fmaf(__shfl(x0, k, 64),     WL[k * HIDC + lane],       a0);
            a1 = fmaf(__shfl(x0, k + 1, 64), WL[(k + 1) * HIDC + lane], a1);
            a2 = fmaf(__shfl(x0, k + 2, 64), WL[(k + 2) * HIDC + lane], a2);
            a3 = fmaf(__shfl(x0, k + 3, 64), WL[(k + 3) * HIDC + lane], a3);
        }
        #pragma unroll
        for (int k = 0; k < 64; k += 4) {
            a0 = fmaf(__shfl(x1, k, 64),     WL[(64 + k) * HIDC + lane],     a0);
            a1 = fmaf(__shfl(x1, k + 1, 64), WL[(64 + k + 1) * HIDC + lane], a1);
            a2 = fmaf(__shfl(x1, k + 2, 64), WL[(64 + k + 2) * HIDC + lane], a2);
            a3 = fmaf(__shfl(x1, k + 3, 64), WL[(64 + k + 3) * HIDC + lane], a3);
        }
        h[r * HIDC + lane] = b[lane] + ((a0 + a1) + (a2 + a3));
    }
}

// ---------------- edge softmax-aggregation (one wave per dst node, 8-deep MLP) ---
__global__ __launch_bounds__(256) void k_aggr(const float* __restrict__ y,
                                              const int* __restrict__ rowOfs,
                                              const int* __restrict__ csr,
                                              const float* __restrict__ tptr,
                                              float* __restrict__ aggr) {
    int lane = threadIdx.x & 63;
    int v = (blockIdx.x * 256 + threadIdx.x) >> 6;
    if (v >= NN) return;
    float t = *tptr;
    int e0 = rowOfs[v], e1 = rowOfs[v + 1];
    float se = 0.f, sw = 0.f;
    for (int e = e0; e < e1; e += 8) {
        #pragma unroll
        for (int i = 0; i < 8; i++) {
            int ee = e + i;
            bool val = ee < e1;
            int s = csr[val ? ee : e0];
            float g = fmaxf(y[s * HIDC + lane], 0.f) + EPS_MSG;
            float w = val ? __expf(t * g) : 0.f;
            se += w;
            sw = fmaf(g, w, sw);
        }
    }
    aggr[v * HIDC + lane] = sw / (se + EPS_SM);
}

// ------- hout = (aggr + yin) @ W + b (+hres); fused y_next = relu(LN(hout)) -----
template<bool RES, bool EMIT_Y>
__global__ __launch_bounds__(256) void k_gemm_ln(const float* __restrict__ aggr,
                                                const float* __restrict__ yin,
                                                const float* __restrict__ W,
                                                const float* __restrict__ b,
                                                const float* __restrict__ hres,
                                                float* __restrict__ hout,
                                                float* __restrict__ yout) {
    __shared__ float WL[HIDC * HIDC];
    for (int i = threadIdx.x; i < HIDC * HIDC; i += 256) WL[i] = W[i];
    __syncthreads();
    int lane = threadIdx.x & 63;
    int wid = (blockIdx.x * 256 + threadIdx.x) >> 6;
    int nw = (gridDim.x * 256) >> 6;
    for (int r = wid; r < NN; r += nw) {
        float a = aggr[r * HIDC + lane] + yin[r * HIDC + lane];
        float base = b[lane];
        if (RES) base += hres[r * HIDC + lane];
        float a0 = 0.f, a1 = 0.f, a2 = 0.f, a3 = 0.f;
        #pragma unroll
        for (int k = 0; k < 64; k += 4) {
            a0 = fmaf(__shfl(a, k, 64),     WL[k * HIDC + lane],       a0);
            a1 = fmaf(__shfl(a, k + 1, 64), WL[(k + 1) * HIDC + lane], a1);
            a2 = fmaf(__shfl(a, k + 2, 64), WL[(k + 2) * HIDC + lane], a2);
            a3 = fmaf(__shfl(a, k + 3, 64), WL[(k + 3) * HIDC + lane], a3);
        }
        float acc = base + ((a0 + a1) + (a2 + a3));
        hout[r * HIDC + lane] = acc;
        if (EMIT_Y) {
            float mu = wave_sum(acc) * (1.f / 64.f);
            float d = acc - mu;
            float var = wave_sum(d * d) * (1.f / 64.f);
            yout[r * HIDC + lane] = fmaxf(d * rsqrtf(var + LN_EPS), 0.f);
        }
    }
}

// ---------------- final LN + ReLU + log_softmax ----------------
__global__ __launch_bounds__(256) void k_final(const float* __restrict__ h,
                                               float* __restrict__ out) {
    int lane = threadIdx.x & 63;
    int wid = (blockIdx.x * 256 + threadIdx.x) >> 6;
    if (wid >= NN) return;
    float v = h[wid * HIDC + lane];
    float mu = wave_sum(v) * (1.f / 64.f);
    float d = v - mu;
    float var = wave_sum(d * d) * (1.f / 64.f);
    float z = fmaxf(d * rsqrtf(var + LN_EPS), 0.f);
    float m = wave_max(z);
    float s = wave_sum(__expf(z - m));
    out[wid * HIDC + lane] = z - (m + __logf(s));
}

extern "C" void kernel_launch(void* const* d_in, const int* in_sizes, int n_in,
                              void* d_out, int out_size, void* d_ws, size_t ws_size,
                              hipStream_t stream) {
    const float* x    = (const float*)d_in[0];
    const int*   ei   = (const int*)d_in[1];
    const float* encW = (const float*)d_in[2];
    const float* encb = (const float*)d_in[3];
    const float* mlpW = (const float*)d_in[4];
    const float* mlpb = (const float*)d_in[5];
    const float* t    = (const float*)d_in[6];

    float* h = (float*)d_out;   // [NN, 64] working buffer doubles as output

    char* ws = (char*)d_ws;
    size_t off = 0;
    auto alloc = [&](size_t bytes) -> void* {
        void* p = ws + off;
        off += (bytes + 255) / 256 * 256;
        return p;
    };
    float* y      = (float*)alloc((size_t)NN * HIDC * 4);
    float* aggr   = (float*)alloc((size_t)NN * HIDC * 4);
    int*   deg    = (int*)alloc((size_t)NN * 4);
    int*   cur    = (int*)alloc((size_t)NN * 4);
    int*   rowOfs = (int*)alloc((size_t)(NN + 1) * 4);
    int*   part   = (int*)alloc((size_t)NB_SCAN * 4);
    int*   partOf = (int*)alloc((size_t)NB_SCAN * 4);
    int*   csr    = (int*)alloc((size_t)NE * 4);

    const int* src = ei;
    const int* dst = ei + NE;

    hipMemsetAsync(deg, 0, (size_t)NN * 4, stream);
    hipMemsetAsync(cur, 0, (size_t)NN * 4, stream);

    k_hist<<<(NE + 255) / 256, 256, 0, stream>>>(dst, deg);
    k_part<<<NB_SCAN, SCAN_B, 0, stream>>>(deg, part);
    k_scanpart<<<1, SCAN_B, 0, stream>>>(part, partOf);
    k_scanfinal<<<NB_SCAN, SCAN_B, 0, stream>>>(deg, partOf, rowOfs);
    k_scatter<<<(NE + 255) / 256, 256, 0, stream>>>(src, dst, rowOfs, cur, csr);

    k_enc<<<1280, 256, 0, stream>>>(x, encW, encb, h);

    // layer 0: input h (no pre-norm), no residual; fused LN -> y for layer 1
    k_aggr<<<12500, 256, 0, stream>>>(h, rowOfs, csr, t, aggr);
    k_gemm_ln<false, true><<<2048, 256, 0, stream>>>(aggr, h, mlpW, mlpb, nullptr, h, y);

    for (int l = 1; l < NL; l++) {
        k_aggr<<<12500, 256, 0, stream>>>(y, rowOfs, csr, t + l, aggr);
        const float* W = mlpW + (size_t)l * HIDC * HIDC;
        const float* bb = mlpb + (size_t)l * HIDC;
        if (l < NL - 1)
            k_gemm_ln<true, true><<<2048, 256, 0, stream>>>(aggr, y, W, bb, h, h, y);
        else
            k_gemm_ln<true, false><<<2048, 256, 0, stream>>>(aggr, y, W, bb, h, h, y);
    }

    k_final<<<12500, 256, 0, stream>>>(h, h);
}

// Round 4
// 1337.558 us; speedup vs baseline: 1.5571x; 1.0072x over previous
//
#include <hip/hip_runtime.h>

#define NN 50000
#define NE 800000
#define INC 128
#define HIDC 64
#define NL 14
#define EPS_MSG 1e-7f
#define EPS_SM 1e-16f
#define LN_EPS 1e-5f

#define SCAN_B 256
#define NB_SCAN ((NN + SCAN_B - 1) / SCAN_B)   // 196

__device__ __forceinline__ float wave_sum(float v) {
    #pragma unroll
    for (int o = 32; o > 0; o >>= 1) v += __shfl_xor(v, o, 64);
    return v;
}
__device__ __forceinline__ float wave_max(float v) {
    #pragma unroll
    for (int o = 32; o > 0; o >>= 1) v = fmaxf(v, __shfl_xor(v, o, 64));
    return v;
}

// ---------------- CSR build ----------------
__global__ void k_hist(const int* __restrict__ dst, int* __restrict__ deg) {
    int i = blockIdx.x * blockDim.x + threadIdx.x;
    if (i < NE) atomicAdd(&deg[dst[i]], 1);
}

__global__ void k_part(const int* __restrict__ deg, int* __restrict__ part) {
    __shared__ int sm[SCAN_B];
    int b = blockIdx.x;
    int i = b * SCAN_B + threadIdx.x;
    sm[threadIdx.x] = (i < NN) ? deg[i] : 0;
    __syncthreads();
    for (int s = SCAN_B / 2; s > 0; s >>= 1) {
        if (threadIdx.x < s) sm[threadIdx.x] += sm[threadIdx.x + s];
        __syncthreads();
    }
    if (threadIdx.x == 0) part[b] = sm[0];
}

__global__ void k_scanpart(const int* __restrict__ part, int* __restrict__ partOfs) {
    __shared__ int sm[SCAN_B];
    int t = threadIdx.x;
    int own = (t < NB_SCAN) ? part[t] : 0;
    sm[t] = own;
    __syncthreads();
    for (int o = 1; o < SCAN_B; o <<= 1) {
        int v = (t >= o) ? sm[t - o] : 0;
        __syncthreads();
        sm[t] += v;
        __syncthreads();
    }
    if (t < NB_SCAN) partOfs[t] = sm[t] - own;   // exclusive
}

__global__ void k_scanfinal(const int* __restrict__ deg, const int* __restrict__ partOfs,
                            int* __restrict__ rowOfs) {
    __shared__ int sm[SCAN_B];
    int b = blockIdx.x, t = threadIdx.x;
    int i = b * SCAN_B + t;
    int d = (i < NN) ? deg[i] : 0;
    sm[t] = d;
    __syncthreads();
    for (int o = 1; o < SCAN_B; o <<= 1) {
        int v = (t >= o) ? sm[t - o] : 0;
        __syncthreads();
        sm[t] += v;
        __syncthreads();
    }
    if (i < NN) rowOfs[i] = partOfs[b] + sm[t] - d;
    if (i == 0) rowOfs[NN] = NE;
}

__global__ void k_scatter(const int* __restrict__ src, const int* __restrict__ dst,
                          const int* __restrict__ rowOfs, int* __restrict__ cur,
                          int* __restrict__ csr) {
    int i = blockIdx.x * blockDim.x + threadIdx.x;
    if (i < NE) {
        int d = dst[i];
        int p = rowOfs[d] + atomicAdd(&cur[d], 1);
        csr[p] = src[i];
    }
}

// ---------------- encoder: h = x @ encW + encb  (2 rows per wave-iter) ---------
__global__ __launch_bounds__(256) void k_enc(const float* __restrict__ x,
                                             const float* __restrict__ W,
                                             const float* __restrict__ b,
                                             float* __restrict__ h) {
    __shared__ float WL[INC * HIDC];
    for (int i = threadIdx.x; i < (INC * HIDC) / 4; i += 256)
        ((float4*)WL)[i] = ((const float4*)W)[i];
    __syncthreads();
    int lane = threadIdx.x & 63;
    int wid = (blockIdx.x * 256 + threadIdx.x) >> 6;
    int nw = (gridDim.x * 256) >> 6;
    float bias = b[lane];
    for (int p = wid; p < NN / 2; p += nw) {
        // one float4 per lane = 256 consecutive floats = rows 2p and 2p+1
        float4 xv = ((const float4*)x)[(size_t)p * 64 + lane];
        float a0 = 0.f, a1 = 0.f, a2 = 0.f, a3 = 0.f;   // row 2p
        float c0 = 0.f, c1 = 0.f, c2 = 0.f, c3 = 0.f;   // row 2p+1
        #pragma unroll
        for (int kk = 0; kk < 32; kk++) {
            float w0 = WL[(4 * kk + 0) * HIDC + lane];
            float w1 = WL[(4 * kk + 1) * HIDC + lane];
            float w2 = WL[(4 * kk + 2) * HIDC + lane];
            float w3 = WL[(4 * kk + 3) * HIDC + lane];
            a0 = fmaf(__shfl(xv.x, kk, 64), w0, a0);
            a1 = fmaf(__shfl(xv.y, kk, 64), w1, a1);
            a2 = fmaf(__shfl(xv.z, kk, 64), w2, a2);
            a3 = fmaf(__shfl(xv.w, kk, 64), w3, a3);
            c0 = fmaf(__shfl(xv.x, 32 + kk, 64), w0, c0);
            c1 = fmaf(__shfl(xv.y, 32 + kk, 64), w1, c1);
            c2 = fmaf(__shfl(xv.z, 32 + kk, 64), w2, c2);
            c3 = fmaf(__shfl(xv.w, 32 + kk, 64), w3, c3);
        }
        h[(size_t)(2 * p) * HIDC + lane]     = bias + ((a0 + a1) + (a2 + a3));
        h[(size_t)(2 * p + 1) * HIDC + lane] = bias + ((c0 + c1) + (c2 + c3));
    }
}

// -------- fused layer: softmax-aggr + (aggr+y)@W+b (+res) + LN/act epilogue ----
// one wave per dst node; table = gather source (prev y, or enc h for FIRST)
template<bool FIRST, bool FINAL>
__global__ __launch_bounds__(256) void k_layer(const float* __restrict__ table,
                                               float* __restrict__ h,
                                               const int* __restrict__ rowOfs,
                                               const int* __restrict__ csr,
                                               const float* __restrict__ W,
                                               const float* __restrict__ b,
                                               const float* __restrict__ tptr,
                                               float* __restrict__ yout) {
    __shared__ float WL[HIDC * HIDC];
    for (int i = threadIdx.x; i < (HIDC * HIDC) / 4; i += 256)
        ((float4*)WL)[i] = ((const float4*)W)[i];

    int lane = threadIdx.x & 63;
    int v = (blockIdx.x * 256 + threadIdx.x) >> 6;   // 12500 blocks -> exactly NN waves
    float t = *tptr;
    int e0 = rowOfs[v], e1 = rowOfs[v + 1];
    float se = 0.f, sw = 0.f;
    for (int e = e0; e < e1; e += 16) {
        #pragma unroll
        for (int i = 0; i < 16; i++) {
            int ee = e + i;
            bool valid = ee < e1;
            int s = csr[valid ? ee : e0];
            float g = fmaxf(table[(size_t)s * HIDC + lane], 0.f) + EPS_MSG;
            float w = valid ? __expf(t * g) : 0.f;
            se += w;
            sw = fmaf(g, w, sw);
        }
    }
    __syncthreads();   // WL visible (stores issued before gather loop)

    float a = sw / (se + EPS_SM) + table[(size_t)v * HIDC + lane];
    float base = b[lane];
    if (!FIRST) base += h[(size_t)v * HIDC + lane];
    float a0 = 0.f, a1 = 0.f, a2 = 0.f, a3 = 0.f;
    #pragma unroll
    for (int k = 0; k < 64; k += 4) {
        a0 = fmaf(__shfl(a, k, 64),     WL[k * HIDC + lane],       a0);
        a1 = fmaf(__shfl(a, k + 1, 64), WL[(k + 1) * HIDC + lane], a1);
        a2 = fmaf(__shfl(a, k + 2, 64), WL[(k + 2) * HIDC + lane], a2);
        a3 = fmaf(__shfl(a, k + 3, 64), WL[(k + 3) * HIDC + lane], a3);
    }
    float acc = base + ((a0 + a1) + (a2 + a3));

    if (FINAL) {
        float mu = wave_sum(acc) * (1.f / 64.f);
        float d = acc - mu;
        float var = wave_sum(d * d) * (1.f / 64.f);
        float z = fmaxf(d * rsqrtf(var + LN_EPS), 0.f);
        float m = wave_max(z);
        float s2 = wave_sum(__expf(z - m));
        h[(size_t)v * HIDC + lane] = z - (m + __logf(s2));
    } else {
        h[(size_t)v * HIDC + lane] = acc;
        float mu = wave_sum(acc) * (1.f / 64.f);
        float d = acc - mu;
        float var = wave_sum(d * d) * (1.f / 64.f);
        yout[(size_t)v * HIDC + lane] = fmaxf(d * rsqrtf(var + LN_EPS), 0.f);
    }
}

extern "C" void kernel_launch(void* const* d_in, const int* in_sizes, int n_in,
                              void* d_out, int out_size, void* d_ws, size_t ws_size,
                              hipStream_t stream) {
    const float* x    = (const float*)d_in[0];
    const int*   ei   = (const int*)d_in[1];
    const float* encW = (const float*)d_in[2];
    const float* encb = (const float*)d_in[3];
    const float* mlpW = (const float*)d_in[4];
    const float* mlpb = (const float*)d_in[5];
    const float* t    = (const float*)d_in[6];

    float* h = (float*)d_out;   // residual stream, doubles as final output

    char* ws = (char*)d_ws;
    size_t off = 0;
    auto alloc = [&](size_t bytes) -> void* {
        void* p = ws + off;
        off += (bytes + 255) / 256 * 256;
        return p;
    };
    float* T0     = (float*)alloc((size_t)NN * HIDC * 4);  // enc out / even y
    float* T1     = (float*)alloc((size_t)NN * HIDC * 4);  // odd y
    int*   deg    = (int*)alloc((size_t)NN * 4);
    int*   cur    = (int*)alloc((size_t)NN * 4);
    int*   rowOfs = (int*)alloc((size_t)(NN + 1) * 4);
    int*   part   = (int*)alloc((size_t)NB_SCAN * 4);
    int*   partOf = (int*)alloc((size_t)NB_SCAN * 4);
    int*   csr    = (int*)alloc((size_t)NE * 4);

    const int* src = ei;
    const int* dst = ei + NE;

    hipMemsetAsync(deg, 0, (size_t)NN * 4, stream);
    hipMemsetAsync(cur, 0, (size_t)NN * 4, stream);

    k_hist<<<(NE + 255) / 256, 256, 0, stream>>>(dst, deg);
    k_part<<<NB_SCAN, SCAN_B, 0, stream>>>(deg, part);
    k_scanpart<<<1, SCAN_B, 0, stream>>>(part, partOf);
    k_scanfinal<<<NB_SCAN, SCAN_B, 0, stream>>>(deg, partOf, rowOfs);
    k_scatter<<<(NE + 255) / 256, 256, 0, stream>>>(src, dst, rowOfs, cur, csr);

    k_enc<<<1280, 256, 0, stream>>>(x, encW, encb, T0);

    // layer 0: gather from enc output T0, no residual; emit y -> T1
    k_layer<true, false><<<12500, 256, 0, stream>>>(T0, h, rowOfs, csr,
                                                    mlpW, mlpb, t, T1);
    // layers 1..12: gather from T[l&1], emit y -> T[(l+1)&1]; residual in-place on h
    for (int l = 1; l < NL - 1; l++) {
        const float* W  = mlpW + (size_t)l * HIDC * HIDC;
        const float* bb = mlpb + (size_t)l * HIDC;
        float* Tin  = (l & 1) ? T1 : T0;
        float* Tout = (l & 1) ? T0 : T1;
        k_layer<false, false><<<12500, 256, 0, stream>>>(Tin, h, rowOfs, csr,
                                                         W, bb, t + l, Tout);
    }
    // layer 13 (odd -> reads T1): fused final LN + relu + log_softmax into h
    k_layer<false, true><<<12500, 256, 0, stream>>>(T1, h, rowOfs, csr,
                                                    mlpW + (size_t)(NL - 1) * HIDC * HIDC,
                                                    mlpb + (size_t)(NL - 1) * HIDC,
                                                    t + (NL - 1), nullptr);
}